// Round 5
// baseline (134.417 us; speedup 1.0000x reference)
//
#include <hip/hip_runtime.h>

#define TQ 512
#define TK 256
#define BB 8
#define CC 128

// 2*log2(e): projections pre-scaled so exp2(qs+ks) == e^(2(q+k))
#define SCALE2L2E 2.8853900817779268f
#define L2E 1.4426950408889634f

__device__ __forceinline__ float fexp2(float x) { return __builtin_amdgcn_exp2f(x); }
__device__ __forceinline__ float frcp(float x)  { return __builtin_amdgcn_rcpf(x); }

// ---------------- Kernel 1: fused projections v5 ----------------
// Y(rows x 128) = X(rows x K) @ W(128 x K)^T ; row r -> (t = r/8, b = r%8).
// Block: 16 rows x 128 cols, 4 waves; wave w owns rows [w*4, w*4+4) (uniform),
// lane owns 2 adjacent cols. X read from LDS via wave-uniform BROADCAST b128
// (conflict-free, 4 instr/k4); W stored [c][72] read as 2 b128/k4.
// -> 6 LDS instr per 64 FMA-cy: VALU-bound. Register prefetch one KC=64 chunk
// ahead (compute phase ~1024 cy > HBM latency).
template<int K, int KC>
__device__ __forceinline__ void proj_body(
    const float* __restrict__ X, const float* __restrict__ W,
    float* __restrict__ Y, float scale, int lay, int Tdim,
    int tile, float* smem)
{
    constexpr int KC4 = KC / 4;
    constexpr int NCH = K / KC;
    constexpr int WP = 72;                       // ws pitch (b128 reads 2-way alias free)
    constexpr int XP = 68;                       // xs pitch
    constexpr int NWJ = (128 * KC4) / 256;       // W float4 jobs/thread (exact)
    constexpr int NXJ = 16 * KC4;                // X float4 jobs total (<=256)
    float* wsm = smem;                           // [128][WP]
    float* xsm = smem + 128 * WP;                // [16][XP]

    const int tid = threadIdx.x;
    const int r0 = tile * 16;
    const int w = __builtin_amdgcn_readfirstlane(tid >> 6);
    const int lane = tid & 63;
    const int c2 = lane * 2;

    int wc_[NWJ], wj_[NWJ];
#pragma unroll
    for (int m = 0; m < NWJ; ++m) { int i = tid + 256 * m; wc_[m] = i / KC4; wj_[m] = i % KC4; }
    const int xr = tid / KC4, xj = tid % KC4;

    float4 pw[NWJ], px;
    auto issue = [&](int kc) {
#pragma unroll
        for (int m = 0; m < NWJ; ++m)
            pw[m] = *(const float4*)&W[wc_[m] * K + kc * KC + wj_[m] * 4];
        if (NXJ == 256 || tid < NXJ)
            px = *(const float4*)&X[(r0 + xr) * K + kc * KC + xj * 4];
    };

    issue(0);
    float acc[4][2];
#pragma unroll
    for (int r = 0; r < 4; ++r) { acc[r][0] = 0.f; acc[r][1] = 0.f; }

    for (int kc = 0; kc < NCH; ++kc) {
        if (kc) __syncthreads();
#pragma unroll
        for (int m = 0; m < NWJ; ++m)
            *(float4*)&wsm[wc_[m] * WP + wj_[m] * 4] = pw[m];
        if (NXJ == 256 || tid < NXJ)
            *(float4*)&xsm[xr * XP + xj * 4] = px;
        __syncthreads();
        if (kc + 1 < NCH) issue(kc + 1);

#pragma unroll
        for (int k4 = 0; k4 < KC4; ++k4) {
            float4 wv0 = *(const float4*)&wsm[c2 * WP + k4 * 4];
            float4 wv1 = *(const float4*)&wsm[(c2 + 1) * WP + k4 * 4];
            float4 xv[4];
#pragma unroll
            for (int r = 0; r < 4; ++r)
                xv[r] = *(const float4*)&xsm[(w * 4 + r) * XP + k4 * 4];  // broadcast
#pragma unroll
            for (int r = 0; r < 4; ++r) {
                acc[r][0] = fmaf(xv[r].x, wv0.x, acc[r][0]);
                acc[r][1] = fmaf(xv[r].x, wv1.x, acc[r][1]);
                acc[r][0] = fmaf(xv[r].y, wv0.y, acc[r][0]);
                acc[r][1] = fmaf(xv[r].y, wv1.y, acc[r][1]);
                acc[r][0] = fmaf(xv[r].z, wv0.z, acc[r][0]);
                acc[r][1] = fmaf(xv[r].z, wv1.z, acc[r][1]);
                acc[r][0] = fmaf(xv[r].w, wv0.w, acc[r][0]);
                acc[r][1] = fmaf(xv[r].w, wv1.w, acc[r][1]);
            }
        }
    }

#pragma unroll
    for (int r = 0; r < 4; ++r) {
        int grow = r0 + w * 4 + r;
        int t = grow >> 3, b = grow & 7;
        float v0 = acc[r][0] * scale, v1 = acc[r][1] * scale;
        if (lay == 0) {
            *(float2*)&Y[(b * Tdim + t) * CC + c2] = make_float2(v0, v1);
        } else {
            Y[(b * CC + c2) * Tdim + t] = v0;
            Y[(b * CC + c2 + 1) * Tdim + t] = v1;
        }
    }
}

__global__ __launch_bounds__(256) void proj_all(
    const float* __restrict__ q_in, const float* __restrict__ Wq, float* __restrict__ qp,
    const float* __restrict__ k_in, const float* __restrict__ Wk, float* __restrict__ kp,
    const float* __restrict__ v_in, const float* __restrict__ Wv, float* __restrict__ vp)
{
    __shared__ float smem[128 * 72 + 16 * 68];
    const int id = blockIdx.x;
    if (id < 128)
        proj_body<640, 64>(k_in, Wk, kp, SCALE2L2E, 1, TK, id, smem);
    else if (id < 256)
        proj_body<640, 64>(v_in, Wv, vp, 1.0f, 0, TK, id - 128, smem);
    else
        proj_body<80, 40>(q_in, Wq, qp, SCALE2L2E, 0, TQ, id - 256, smem);
}

// ---------------- Kernel 2: scores + softmax v2 (no K staging) ----------------
// Wave = 2 q-rows x 256 k (lane holds k = lane*4+j via one float4/c direct from
// L2-resident kp). No barriers in main loop. q/Wvec via uniform s_loads.
__global__ __launch_bounds__(256) void attn_kernel(const float* __restrict__ qp,
                                                   const float* __restrict__ kp,
                                                   const float* __restrict__ Wvec,
                                                   float* __restrict__ attn_out,
                                                   float* __restrict__ pT) {
    __shared__ float pl[8][264];

    const int tid = threadIdx.x;
    const int lane = tid & 63;
    const int w = __builtin_amdgcn_readfirstlane(tid >> 6);
    const int b = blockIdx.y;
    const int q0B = blockIdx.x * 8;
    const int q0 = q0B + w * 2;

    const float* __restrict__ qr0 = qp + (b * TQ + q0) * CC;
    const float* __restrict__ qr1 = qr0 + CC;
    const float* __restrict__ kb = kp + b * CC * TK + lane * 4;

    float sw = Wvec[lane] + Wvec[64 + lane];
#pragma unroll
    for (int m = 32; m >= 1; m >>= 1) sw += __shfl_xor(sw, m, 64);

    float a0[4] = {0.f, 0.f, 0.f, 0.f};
    float a1[4] = {0.f, 0.f, 0.f, 0.f};

#pragma unroll 8
    for (int c = 0; c < CC; ++c) {
        const float4 kf = *(const float4*)&kb[c * TK];
        const float qa = qr0[c];     // s_load (uniform)
        const float qb = qr1[c];     // s_load (uniform)
        const float wc = Wvec[c];    // s_load (uniform)
        float t;
        t = fexp2(qa + kf.x); a0[0] = fmaf(wc, frcp(t + 1.f), a0[0]);
        t = fexp2(qa + kf.y); a0[1] = fmaf(wc, frcp(t + 1.f), a0[1]);
        t = fexp2(qa + kf.z); a0[2] = fmaf(wc, frcp(t + 1.f), a0[2]);
        t = fexp2(qa + kf.w); a0[3] = fmaf(wc, frcp(t + 1.f), a0[3]);
        t = fexp2(qb + kf.x); a1[0] = fmaf(wc, frcp(t + 1.f), a1[0]);
        t = fexp2(qb + kf.y); a1[1] = fmaf(wc, frcp(t + 1.f), a1[1]);
        t = fexp2(qb + kf.z); a1[2] = fmaf(wc, frcp(t + 1.f), a1[2]);
        t = fexp2(qb + kf.w); a1[3] = fmaf(wc, frcp(t + 1.f), a1[3]);
    }

    float sc0[4], sc1[4];
#pragma unroll
    for (int j = 0; j < 4; ++j) {
        sc0[j] = sw - 2.f * a0[j];
        sc1[j] = sw - 2.f * a1[j];
    }

    // softmax over 256 (4 regs x 64 lanes) per row
    float m0 = fmaxf(fmaxf(sc0[0], sc0[1]), fmaxf(sc0[2], sc0[3]));
    float m1 = fmaxf(fmaxf(sc1[0], sc1[1]), fmaxf(sc1[2], sc1[3]));
#pragma unroll
    for (int m = 32; m >= 1; m >>= 1) {
        m0 = fmaxf(m0, __shfl_xor(m0, m, 64));
        m1 = fmaxf(m1, __shfl_xor(m1, m, 64));
    }
    float e0[4], e1[4], s0 = 0.f, s1 = 0.f;
#pragma unroll
    for (int j = 0; j < 4; ++j) {
        e0[j] = fexp2((sc0[j] - m0) * L2E); s0 += e0[j];
        e1[j] = fexp2((sc1[j] - m1) * L2E); s1 += e1[j];
    }
#pragma unroll
    for (int m = 32; m >= 1; m >>= 1) {
        s0 += __shfl_xor(s0, m, 64);
        s1 += __shfl_xor(s1, m, 64);
    }
    const float r0 = frcp(s0), r1 = frcp(s1);

    const float4 p0 = make_float4(e0[0] * r0, e0[1] * r0, e0[2] * r0, e0[3] * r0);
    const float4 p1 = make_float4(e1[0] * r1, e1[1] * r1, e1[2] * r1, e1[3] * r1);
    *(float4*)&attn_out[(b * TQ + q0) * TK + lane * 4] = p0;
    *(float4*)&attn_out[(b * TQ + q0 + 1) * TK + lane * 4] = p1;
    *(float4*)&pl[w * 2 + 0][lane * 4] = p0;
    *(float4*)&pl[w * 2 + 1][lane * 4] = p1;
    __syncthreads();

    // cooperative transpose dump: pT[b][k][q0B + j]
    for (int i = tid; i < 2048; i += 256) {
        int k = i >> 3, j = i & 7;
        pT[(b * TK + k) * TQ + q0B + j] = pl[j][k];
    }
}

// ---------------- Kernel 3: PV ----------------
// out[b][c][q] = sum_k p[b][q][k] * v[b][k][c]
__global__ __launch_bounds__(256) void pv_kernel(const float* __restrict__ pT,
                                                 const float* __restrict__ vp,
                                                 float* __restrict__ out) {
    const int tid = threadIdx.x;
    const int qh = blockIdx.x;   // 0..3
    const int cg = blockIdx.y;   // 0..7
    const int b  = blockIdx.z;   // 0..7
    const int ch = __builtin_amdgcn_readfirstlane(tid >> 7);
    const int q = qh * 128 + (tid & 127);
    const int c0 = cg * 16 + ch * 8;

    const float* __restrict__ vb = vp + b * TK * CC + c0;
    const float* __restrict__ pb = pT + b * TK * TQ + q;

    float acc[8];
#pragma unroll
    for (int j = 0; j < 8; ++j) acc[j] = 0.f;

#pragma unroll 8
    for (int k = 0; k < TK; ++k) {
        const float p = pb[k * TQ];
        const float* __restrict__ vr = vb + k * CC;  // uniform -> s_load
#pragma unroll
        for (int j = 0; j < 8; ++j) acc[j] = fmaf(p, vr[j], acc[j]);
    }

#pragma unroll
    for (int j = 0; j < 8; ++j)
        out[(b * CC + c0 + j) * TQ + q] = acc[j];
}

extern "C" void kernel_launch(void* const* d_in, const int* in_sizes, int n_in,
                              void* d_out, int out_size, void* d_ws, size_t ws_size,
                              hipStream_t stream) {
    const float* queries = (const float*)d_in[0];
    const float* keys    = (const float*)d_in[1];
    const float* values  = (const float*)d_in[2];
    const float* Wq      = (const float*)d_in[3];
    const float* Wk      = (const float*)d_in[4];
    const float* Wv      = (const float*)d_in[5];
    const float* Wvec    = (const float*)d_in[6];

    float* out  = (float*)d_out;                 // (8,128,512)
    float* attn = out + BB * CC * TQ;            // (8,512,256)

    float* ws = (float*)d_ws;
    float* qp = ws;                    // [b][t][c] 4096*128, scaled by 2*log2e
    float* kp = qp + 4096 * CC;        // [b][c][t] 2048*128, scaled
    float* vp = kp + 2048 * CC;        // [b][t][c] 2048*128
    float* pT = vp + 2048 * CC;        // [b][k][q] 8*256*512

    // flat 512 blocks: 0-127 keys, 128-255 values, 256-511 queries
    proj_all<<<dim3(512), 256, 0, stream>>>(
        queries, Wq, qp, keys, Wk, kp, values, Wv, vp);
    attn_kernel<<<dim3(64, 8), 256, 0, stream>>>(qp, kp, Wvec, attn, pT);
    pv_kernel<<<dim3(4, 8, 8), 256, 0, stream>>>(pT, vp, out);
}

// Round 6
// 128.217 us; speedup vs baseline: 1.0484x; 1.0484x over previous
//
#include <hip/hip_runtime.h>

#define TQ 512
#define TK 256
#define BB 8
#define CC 128

// 2*log2(e): projections pre-scaled so exp2(qs+ks) == e^(2(q+k))
#define SCALE2L2E 2.8853900817779268f
#define L2E 1.4426950408889634f

__device__ __forceinline__ float fexp2(float x) { return __builtin_amdgcn_exp2f(x); }
__device__ __forceinline__ float frcp(float x)  { return __builtin_amdgcn_rcpf(x); }

// ---------------- projection GEMM v6 ----------------
// Y(rows x 128) = X(rows x K) @ W(128 x K)^T ; row r -> (t = r/8, b = r%8).
// Block: 16r x 64c, 128 thr; wave = 8r x 64c (rows WAVE-UNIFORM); thread = 8r x 1c.
// X: s_loads (uniform rows) - no LDS, no VALU.  W: LDS wsT[k][66], read
// wsT[k][lane] (banks 2k+l -> 2/bank free), staged c=lane (banks=l, free).
// Double-buffered, register-prefetched, 1 barrier per KC-chunk.
template<int K, int KC, int LAY>
__device__ __forceinline__ void proj_block(
    const float* __restrict__ X, const float* __restrict__ W,
    float* __restrict__ Y, float scale, int Tdim, int rt, int ct, float* wsT)
{
    constexpr int NCH = K / KC;
    constexpr int NJ = (64 * (KC / 4)) / 128;   // W float4 jobs/thread (KV:4, Q:2)
    constexpr int BUF = KC * 66;

    const int tid = threadIdx.x;
    const int w = __builtin_amdgcn_readfirstlane(tid >> 6);
    const int l = tid & 63;
    const int c0 = ct * 64;
    const int r0 = rt * 16 + w * 8;
    const int wc = tid & 63;                    // staging column = lane
    const int kq = tid >> 6;                    // staging k4 phase

    const float* __restrict__ Wrow = W + (c0 + wc) * K;
    const float* __restrict__ Xr[8];
#pragma unroll
    for (int i = 0; i < 8; ++i) Xr[i] = X + (r0 + i) * K;

    float4 pw[NJ];
    auto issue = [&](int kc) {
#pragma unroll
        for (int m = 0; m < NJ; ++m)
            pw[m] = *(const float4*)&Wrow[kc * KC + (kq + 2 * m) * 4];
    };
    auto publish = [&](int buf) {
        float* dst = wsT + buf * BUF;
#pragma unroll
        for (int m = 0; m < NJ; ++m) {
            int k4 = kq + 2 * m;
            dst[(k4 * 4 + 0) * 66 + wc] = pw[m].x;
            dst[(k4 * 4 + 1) * 66 + wc] = pw[m].y;
            dst[(k4 * 4 + 2) * 66 + wc] = pw[m].z;
            dst[(k4 * 4 + 3) * 66 + wc] = pw[m].w;
        }
    };

    float acc[8];
#pragma unroll
    for (int i = 0; i < 8; ++i) acc[i] = 0.f;

    issue(0);
    publish(0);
    if (NCH > 1) issue(1);
    __syncthreads();

    for (int kc = 0; kc < NCH; ++kc) {
        if (kc + 1 < NCH) {
            publish((kc + 1) & 1);               // buf^1: last read 2 iters ago (safe)
            if (kc + 2 < NCH) issue(kc + 2);
        }
        const float* __restrict__ ws = wsT + (kc & 1) * BUF;
#pragma unroll
        for (int k4 = 0; k4 < KC / 4; ++k4) {
            float xs_[8][4];                     // SGPR (uniform rows)
#pragma unroll
            for (int i = 0; i < 8; ++i)
#pragma unroll
                for (int j = 0; j < 4; ++j)
                    xs_[i][j] = Xr[i][kc * KC + k4 * 4 + j];
#pragma unroll
            for (int j = 0; j < 4; ++j) {
                const float wv = ws[(k4 * 4 + j) * 66 + l];
#pragma unroll
                for (int i = 0; i < 8; ++i)
                    acc[i] = fmaf(xs_[i][j], wv, acc[i]);
            }
        }
        __syncthreads();
    }

    const int t = r0 >> 3;                       // r0 multiple of 8: t uniform, b = i
#pragma unroll
    for (int i = 0; i < 8; ++i) {
        float v = acc[i] * scale;
        if (LAY == 0) Y[(i * Tdim + t) * CC + c0 + l] = v;
        else          Y[(i * CC + c0 + l) * Tdim + t] = v;
    }
}

// 1024 blocks: 8-block groups alternate KV-work / Q-work so each CU mixes
// long (5120 FMA/thr) and short (1280) blocks.
__global__ __launch_bounds__(128) void proj_v6(
    const float* __restrict__ q_in, const float* __restrict__ Wq, float* __restrict__ qp,
    const float* __restrict__ k_in, const float* __restrict__ Wk, float* __restrict__ kp,
    const float* __restrict__ v_in, const float* __restrict__ Wv, float* __restrict__ vp)
{
    __shared__ float lds[2 * 32 * 66];
    const int id = blockIdx.x;
    const int g = id >> 3, s = id & 7;
    const int idx = (g >> 1) * 8 + s;            // 0..511 within type
    if ((g & 1) == 0) {
        const int tensor = idx >> 8;             // 0: keys, 1: values
        const int sub = idx & 255;
        const int rt = sub >> 1, ct = sub & 1;
        if (tensor == 0)
            proj_block<640, 32, 1>(k_in, Wk, kp, SCALE2L2E, TK, rt, ct, lds);
        else
            proj_block<640, 32, 0>(v_in, Wv, vp, 1.0f, TK, rt, ct, lds);
    } else {
        const int rt = idx >> 1, ct = idx & 1;
        proj_block<80, 16, 0>(q_in, Wq, qp, SCALE2L2E, TQ, rt, ct, lds);
    }
}

// ---------------- Kernel 2: scores + softmax v2 (no K staging) ----------------
// Wave = 2 q-rows x 256 k (lane holds k = lane*4+j via one float4/c direct from
// L2-resident kp). No barriers in main loop. q/Wvec via uniform s_loads.
__global__ __launch_bounds__(256) void attn_kernel(const float* __restrict__ qp,
                                                   const float* __restrict__ kp,
                                                   const float* __restrict__ Wvec,
                                                   float* __restrict__ attn_out,
                                                   float* __restrict__ pT) {
    __shared__ float pl[8][264];

    const int tid = threadIdx.x;
    const int lane = tid & 63;
    const int w = __builtin_amdgcn_readfirstlane(tid >> 6);
    const int b = blockIdx.y;
    const int q0B = blockIdx.x * 8;
    const int q0 = q0B + w * 2;

    const float* __restrict__ qr0 = qp + (b * TQ + q0) * CC;
    const float* __restrict__ qr1 = qr0 + CC;
    const float* __restrict__ kb = kp + b * CC * TK + lane * 4;

    float sw = Wvec[lane] + Wvec[64 + lane];
#pragma unroll
    for (int m = 32; m >= 1; m >>= 1) sw += __shfl_xor(sw, m, 64);

    float a0[4] = {0.f, 0.f, 0.f, 0.f};
    float a1[4] = {0.f, 0.f, 0.f, 0.f};

#pragma unroll 8
    for (int c = 0; c < CC; ++c) {
        const float4 kf = *(const float4*)&kb[c * TK];
        const float qa = qr0[c];     // s_load (uniform)
        const float qb = qr1[c];     // s_load (uniform)
        const float wc = Wvec[c];    // s_load (uniform)
        float t;
        t = fexp2(qa + kf.x); a0[0] = fmaf(wc, frcp(t + 1.f), a0[0]);
        t = fexp2(qa + kf.y); a0[1] = fmaf(wc, frcp(t + 1.f), a0[1]);
        t = fexp2(qa + kf.z); a0[2] = fmaf(wc, frcp(t + 1.f), a0[2]);
        t = fexp2(qa + kf.w); a0[3] = fmaf(wc, frcp(t + 1.f), a0[3]);
        t = fexp2(qb + kf.x); a1[0] = fmaf(wc, frcp(t + 1.f), a1[0]);
        t = fexp2(qb + kf.y); a1[1] = fmaf(wc, frcp(t + 1.f), a1[1]);
        t = fexp2(qb + kf.z); a1[2] = fmaf(wc, frcp(t + 1.f), a1[2]);
        t = fexp2(qb + kf.w); a1[3] = fmaf(wc, frcp(t + 1.f), a1[3]);
    }

    float sc0[4], sc1[4];
#pragma unroll
    for (int j = 0; j < 4; ++j) {
        sc0[j] = sw - 2.f * a0[j];
        sc1[j] = sw - 2.f * a1[j];
    }

    float m0 = fmaxf(fmaxf(sc0[0], sc0[1]), fmaxf(sc0[2], sc0[3]));
    float m1 = fmaxf(fmaxf(sc1[0], sc1[1]), fmaxf(sc1[2], sc1[3]));
#pragma unroll
    for (int m = 32; m >= 1; m >>= 1) {
        m0 = fmaxf(m0, __shfl_xor(m0, m, 64));
        m1 = fmaxf(m1, __shfl_xor(m1, m, 64));
    }
    float e0[4], e1[4], s0 = 0.f, s1 = 0.f;
#pragma unroll
    for (int j = 0; j < 4; ++j) {
        e0[j] = fexp2((sc0[j] - m0) * L2E); s0 += e0[j];
        e1[j] = fexp2((sc1[j] - m1) * L2E); s1 += e1[j];
    }
#pragma unroll
    for (int m = 32; m >= 1; m >>= 1) {
        s0 += __shfl_xor(s0, m, 64);
        s1 += __shfl_xor(s1, m, 64);
    }
    const float r0 = frcp(s0), r1 = frcp(s1);

    const float4 p0 = make_float4(e0[0] * r0, e0[1] * r0, e0[2] * r0, e0[3] * r0);
    const float4 p1 = make_float4(e1[0] * r1, e1[1] * r1, e1[2] * r1, e1[3] * r1);
    *(float4*)&attn_out[(b * TQ + q0) * TK + lane * 4] = p0;
    *(float4*)&attn_out[(b * TQ + q0 + 1) * TK + lane * 4] = p1;
    *(float4*)&pl[w * 2 + 0][lane * 4] = p0;
    *(float4*)&pl[w * 2 + 1][lane * 4] = p1;
    __syncthreads();

    // cooperative transpose dump: pT[b][k][q0B + j]
    for (int i = tid; i < 2048; i += 256) {
        int k = i >> 3, j = i & 7;
        pT[(b * TK + k) * TQ + q0B + j] = pl[j][k];
    }
}

// ---------------- Kernel 3: PV ----------------
// out[b][c][q] = sum_k p[b][q][k] * v[b][k][c]
__global__ __launch_bounds__(256) void pv_kernel(const float* __restrict__ pT,
                                                 const float* __restrict__ vp,
                                                 float* __restrict__ out) {
    const int tid = threadIdx.x;
    const int qh = blockIdx.x;   // 0..3
    const int cg = blockIdx.y;   // 0..7
    const int b  = blockIdx.z;   // 0..7
    const int ch = __builtin_amdgcn_readfirstlane(tid >> 7);
    const int q = qh * 128 + (tid & 127);
    const int c0 = cg * 16 + ch * 8;

    const float* __restrict__ vb = vp + b * TK * CC + c0;
    const float* __restrict__ pb = pT + b * TK * TQ + q;

    float acc[8];
#pragma unroll
    for (int j = 0; j < 8; ++j) acc[j] = 0.f;

#pragma unroll 8
    for (int k = 0; k < TK; ++k) {
        const float p = pb[k * TQ];
        const float* __restrict__ vr = vb + k * CC;  // uniform -> s_load
#pragma unroll
        for (int j = 0; j < 8; ++j) acc[j] = fmaf(p, vr[j], acc[j]);
    }

#pragma unroll
    for (int j = 0; j < 8; ++j)
        out[(b * CC + c0 + j) * TQ + q] = acc[j];
}

extern "C" void kernel_launch(void* const* d_in, const int* in_sizes, int n_in,
                              void* d_out, int out_size, void* d_ws, size_t ws_size,
                              hipStream_t stream) {
    const float* queries = (const float*)d_in[0];
    const float* keys    = (const float*)d_in[1];
    const float* values  = (const float*)d_in[2];
    const float* Wq      = (const float*)d_in[3];
    const float* Wk      = (const float*)d_in[4];
    const float* Wv      = (const float*)d_in[5];
    const float* Wvec    = (const float*)d_in[6];

    float* out  = (float*)d_out;                 // (8,128,512)
    float* attn = out + BB * CC * TQ;            // (8,512,256)

    float* ws = (float*)d_ws;
    float* qp = ws;                    // [b][t][c] 4096*128, scaled by 2*log2e
    float* kp = qp + 4096 * CC;        // [b][c][t] 2048*128, scaled
    float* vp = kp + 2048 * CC;        // [b][t][c] 2048*128
    float* pT = vp + 2048 * CC;        // [b][k][q] 8*256*512

    proj_v6<<<dim3(1024), 128, 0, stream>>>(
        queries, Wq, qp, keys, Wk, kp, values, Wv, vp);
    attn_kernel<<<dim3(64, 8), 256, 0, stream>>>(qp, kp, Wvec, attn, pT);
    pv_kernel<<<dim3(4, 8, 8), 256, 0, stream>>>(pT, vp, out);
}